// Round 1
// baseline (1171.540 us; speedup 1.0000x reference)
//
#include <hip/hip_runtime.h>
#include <hip/hip_bf16.h>

// SlotAttention: B=64, N=4096, FEAT=DIM=KVQ=256, HEADS=4, SLOTS=8, ITERS=3, DPH=64
// Pipeline:
//   prep: bf16-cast Wk|Wv (packed 512x256) and GRU weights
//   ln_in: LayerNorm(inputs) -> xn bf16 [262144][256]
//   gemm_kv: xn @ [Wk;Wv]^T -> kv bf16 [b][j][512] (granule-swizzled: phys16B = log16B ^ (j&7))
//   per iter: q_kernel (LN(slots)@Wq^T*SCALE) ; iter_kernel (dots+softmax+out+updates, fused
//             single pass, atomics for cross-block j-reduction) ; gru_kernel (GRUCell)
// Fusion insight: attn/(sum_j attn + EPS) folded into final divide of updates.

typedef unsigned int u32;
typedef unsigned short u16;
typedef short bf16x8 __attribute__((ext_vector_type(8)));
typedef float f32x4 __attribute__((ext_vector_type(4)));

#define SCALE_ 0.125f

__device__ inline u16 f2bf(float f){
  u32 x = __float_as_uint(f);
  return (u16)((x + 0x7fffu + ((x >> 16) & 1u)) >> 16);
}
__device__ inline float bf2f_s(short h){ return __uint_as_float(((u32)(u16)h) << 16); }

__device__ inline void gload16(const void* g, void* l){
  __builtin_amdgcn_global_load_lds((const __attribute__((address_space(1))) u32*)g,
                                   (__attribute__((address_space(3))) u32*)l, 16, 0, 0);
}

// ---------------- prep: bf16 weight casts ----------------
__global__ void prep_kernel(const float* __restrict__ Wk, const float* __restrict__ Wv,
                            const float* __restrict__ wih, const float* __restrict__ whh,
                            u16* __restrict__ Bkv, u16* __restrict__ wihb, u16* __restrict__ whhb){
  int t = blockIdx.x * 256 + threadIdx.x;
  int stride = gridDim.x * 256;
  for (int idx = t; idx < 512 * 256; idx += stride){
    int n = idx >> 8, c = idx & 255;
    float v = (n < 256) ? Wk[(n << 8) + c] : Wv[((n - 256) << 8) + c];
    Bkv[idx] = f2bf(v);
  }
  for (int idx = t; idx < 768 * 256; idx += stride){
    wihb[idx] = f2bf(wih[idx]);
    whhb[idx] = f2bf(whh[idx]);
  }
}

// ---------------- LayerNorm(inputs) -> bf16 ----------------
__global__ __launch_bounds__(256) void ln_in_kernel(const float* __restrict__ x,
    const float* __restrict__ w, const float* __restrict__ bb, u16* __restrict__ xn){
  int wid = threadIdx.x >> 6, lane = threadIdx.x & 63;
  long row = (long)blockIdx.x * 4 + wid;   // 262144 rows, one per wave
  const float4* xr = (const float4*)(x + row * 256);
  float4 v = xr[lane];
  float s  = v.x + v.y + v.z + v.w;
  float s2 = v.x*v.x + v.y*v.y + v.z*v.z + v.w*v.w;
  #pragma unroll
  for (int m = 1; m < 64; m <<= 1){ s += __shfl_xor(s, m); s2 += __shfl_xor(s2, m); }
  float mu = s * (1.f/256.f);
  float rstd = rsqrtf(s2 * (1.f/256.f) - mu*mu + 1e-5f);
  float4 wv = ((const float4*)w)[lane];
  float4 bv = ((const float4*)bb)[lane];
  ushort4 o;
  o.x = f2bf((v.x - mu) * rstd * wv.x + bv.x);
  o.y = f2bf((v.y - mu) * rstd * wv.y + bv.y);
  o.z = f2bf((v.z - mu) * rstd * wv.z + bv.z);
  o.w = f2bf((v.w - mu) * rstd * wv.w + bv.w);
  *(ushort4*)(xn + row * 256 + lane * 4) = o;
}

// ---------------- GEMM: KV = xn @ Bkv^T, swizzled bf16 out ----------------
__global__ __launch_bounds__(256) void gemm_kv(const u16* __restrict__ A,
                                               const u16* __restrict__ Bm,
                                               u16* __restrict__ kv){
  __shared__ u16 smem[16384];             // 32 KB: A[128][64] + B[128][64], reused as C[128][128]
  u16* Al = smem;
  u16* Bl = smem + 8192;
  int tid = threadIdx.x, wid = tid >> 6, lane = tid & 63;
  int nt = blockIdx.x & 3;
  long mt = blockIdx.x >> 2;
  long m0 = mt * 128;
  int n0 = nt * 128;
  f32x4 acc[4][4] = {};
  int msub = (wid & 1) * 64, nsub = (wid >> 1) * 64;
  for (int kt = 0; kt < 4; ++kt){
    const char* Ag = (const char*)(A + m0 * 256 + kt * 64);
    const char* Bg = (const char*)(Bm + (long)n0 * 256 + kt * 64);
    #pragma unroll
    for (int p = 0; p < 4; ++p){
      int r0 = wid * 32 + p * 8;
      gload16(Ag + (long)(r0 + (lane >> 3)) * 512 + (lane & 7) * 16, (char*)Al + r0 * 128);
      gload16(Bg + (long)(r0 + (lane >> 3)) * 512 + (lane & 7) * 16, (char*)Bl + r0 * 128);
    }
    __syncthreads();
    #pragma unroll
    for (int kk = 0; kk < 2; ++kk){
      bf16x8 af[4], bfr[4];
      #pragma unroll
      for (int mi = 0; mi < 4; ++mi)
        af[mi] = *(const bf16x8*)(Al + (msub + mi*16 + (lane & 15)) * 64 + kk * 32 + (lane >> 4) * 8);
      #pragma unroll
      for (int ni = 0; ni < 4; ++ni)
        bfr[ni] = *(const bf16x8*)(Bl + (nsub + ni*16 + (lane & 15)) * 64 + kk * 32 + (lane >> 4) * 8);
      #pragma unroll
      for (int mi = 0; mi < 4; ++mi)
        #pragma unroll
        for (int ni = 0; ni < 4; ++ni)
          acc[mi][ni] = __builtin_amdgcn_mfma_f32_16x16x32_bf16(af[mi], bfr[ni], acc[mi][ni], 0, 0, 0);
    }
    __syncthreads();
  }
  // Epilogue: stage to LDS bf16 tile, then coalesced swizzled global writes.
  u16* Ct = smem;                          // [128][128]
  #pragma unroll
  for (int mi = 0; mi < 4; ++mi){
    #pragma unroll
    for (int ni = 0; ni < 4; ++ni){
      int col = nsub + ni*16 + (lane & 15);
      #pragma unroll
      for (int r = 0; r < 4; ++r){
        int rowm = msub + mi*16 + (lane >> 4) * 4 + r;
        Ct[rowm * 128 + col] = f2bf(acc[mi][ni][r]);
      }
    }
  }
  __syncthreads();
  // KV row = 1024B = 64 x 16B granules. phys granule = logical ^ (j&7) (within 8-blocks).
  #pragma unroll
  for (int p = 0; p < 8; ++p){
    int g = p * 256 + tid;
    int row = g >> 4, pw = g & 15;
    long m = m0 + row;
    int j = (int)(m & 4095);
    int lloc = pw ^ (j & 7);
    uint4 val = *(const uint4*)(Ct + row * 128 + lloc * 8);
    *(uint4*)((char*)kv + m * 1024 + n0 * 2 + pw * 16) = val;
  }
}

// ---------------- q = LN(slots) @ Wq^T * SCALE ----------------
__global__ __launch_bounds__(256) void q_kernel(const float* __restrict__ ssrc,
    const float* __restrict__ lnw, const float* __restrict__ lnb,
    const float* __restrict__ Wq, float* __restrict__ qout){
  __shared__ float sn[256];
  __shared__ float red[8];
  int row = blockIdx.x, t = threadIdx.x;
  int wid = t >> 6, lane = t & 63;
  float x = ssrc[row * 256 + t];
  float s = x, s2 = x * x;
  #pragma unroll
  for (int m = 1; m < 64; m <<= 1){ s += __shfl_xor(s, m); s2 += __shfl_xor(s2, m); }
  if (lane == 0){ red[wid] = s; red[4 + wid] = s2; }
  __syncthreads();
  s  = red[0] + red[1] + red[2] + red[3];
  s2 = red[4] + red[5] + red[6] + red[7];
  float mu = s * (1.f/256.f);
  float rstd = rsqrtf(s2 * (1.f/256.f) - mu*mu + 1e-5f);
  sn[t] = (x - mu) * rstd * lnw[t] + lnb[t];
  __syncthreads();
  const float4* wr = (const float4*)(Wq + t * 256);
  float acc = 0.f;
  #pragma unroll 8
  for (int c = 0; c < 64; ++c){
    float4 wv = wr[c];
    acc += wv.x * sn[c*4] + wv.y * sn[c*4+1] + wv.z * sn[c*4+2] + wv.w * sn[c*4+3];
  }
  qout[row * 256 + t] = acc * SCALE_;
}

// ---------------- fused dots + softmax + attn-out + updates ----------------
// grid = 64 b * 16 blocks; each block: 8 tiles of 32 j. 256 thr = 4 waves.
__global__ __launch_bounds__(256) void iter_kernel(
    const u16* __restrict__ kv, const float* __restrict__ qg,
    float* __restrict__ upd, float* __restrict__ asum,
    float* __restrict__ out_stack, float* __restrict__ out_last, int write_last){
  __shared__ u16 kvl[32 * 512];     // 32 KB, pre-swizzled rows
  __shared__ float ql[2048];        // q[b]: [i][h][d]
  __shared__ float expl[1024];      // [j][(h*8+i)^j]
  __shared__ float rtot[32];
  int tid = threadIdx.x, wid = tid >> 6, lane = tid & 63;
  int b = blockIdx.x >> 4;
  int blk = blockIdx.x & 15;

  {
    const char* qsrc = (const char*)(qg + b * 2048);
    #pragma unroll
    for (int p = 0; p < 2; ++p){
      int seg = wid * 2 + p;
      gload16(qsrc + seg * 1024 + lane * 16, (char*)ql + seg * 1024);
    }
  }
  float updacc[8];
  #pragma unroll
  for (int e = 0; e < 8; ++e) updacc[e] = 0.f;
  float asacc = 0.f;
  int i_u = tid >> 5, h_u = (tid >> 3) & 3, c_u = tid & 7;
  int jj = lane & 31, half = lane >> 5, h = wid;

  for (int tile = 0; tile < 8; ++tile){
    int j0 = (blk * 8 + tile) * 32;
    const char* src = (const char*)(kv + ((long)b * 4096 + j0) * 512);
    #pragma unroll
    for (int p = 0; p < 8; ++p){
      int seg = wid * 8 + p;
      gload16(src + seg * 1024 + lane * 16, (char*)kvl + seg * 1024);
    }
    __syncthreads();
    // dots: wave h, lane = (jj, half); each half does 4 of 8 k-granules
    float dots[8];
    #pragma unroll
    for (int i = 0; i < 8; ++i) dots[i] = 0.f;
    #pragma unroll
    for (int cc = 0; cc < 4; ++cc){
      int c = half * 4 + cc;
      int gq = jj * 64 + ((h * 8 + c) ^ (jj & 7));
      bf16x8 kvv = *(const bf16x8*)(kvl + gq * 8);
      float kf[8];
      #pragma unroll
      for (int e = 0; e < 8; ++e) kf[e] = bf2f_s(kvv[e]);
      #pragma unroll
      for (int i = 0; i < 8; ++i){
        const float4* q4 = (const float4*)(ql + ((i * 4 + h) << 6) + c * 8);
        float4 qa = q4[0], qb = q4[1];
        dots[i] += qa.x*kf[0] + qa.y*kf[1] + qa.z*kf[2] + qa.w*kf[3]
                 + qb.x*kf[4] + qb.y*kf[5] + qb.z*kf[6] + qb.w*kf[7];
      }
    }
    #pragma unroll
    for (int i = 0; i < 8; ++i) dots[i] += __shfl_xor(dots[i], 32);
    float ev[8];
    #pragma unroll
    for (int i = 0; i < 8; ++i) ev[i] = __expf(dots[i]);   // |dots|<~1: no max-sub needed
    #pragma unroll
    for (int r = 0; r < 4; ++r){
      int i = half * 4 + r;
      expl[jj * 32 + ((h * 8 + i) ^ jj)] = ev[i];
    }
    __syncthreads();
    // total + attn-mean output (wave 0, 32 lanes)
    if (wid == 0 && lane < 32){
      int j = lane;
      float tot = 0.f; float si[8];
      #pragma unroll
      for (int i = 0; i < 8; ++i) si[i] = 0.f;
      #pragma unroll
      for (int h2 = 0; h2 < 4; ++h2){
        #pragma unroll
        for (int i = 0; i < 8; ++i){
          float v = expl[j * 32 + ((h2 * 8 + i) ^ j)];
          tot += v; si[i] += v;
        }
      }
      float rt = 1.f / tot;
      rtot[j] = rt;
      long obase = ((long)b * 8) * 4096 + j0 + j;
      #pragma unroll
      for (int i = 0; i < 8; ++i){
        float o = 0.25f * si[i] * rt;
        out_stack[obase + (long)i * 4096] = o;
        if (write_last) out_last[obase + (long)i * 4096] = o;
      }
    }
    __syncthreads();
    // updates: thread = (i_u, h_u, c_u); v-granule broadcast across i
    #pragma unroll 4
    for (int j = 0; j < 32; ++j){
      float at = expl[j * 32 + ((h_u * 8 + i_u) ^ j)] * rtot[j];
      int gv = j * 64 + ((32 + h_u * 8 + c_u) ^ (j & 7));
      bf16x8 vv = *(const bf16x8*)(kvl + gv * 8);
      #pragma unroll
      for (int e = 0; e < 8; ++e) updacc[e] += at * bf2f_s(vv[e]);
      if (c_u == 0) asacc += at;
    }
    __syncthreads();
  }
  float* up = upd + (((long)b * 8 + i_u) << 8) + h_u * 64 + c_u * 8;
  #pragma unroll
  for (int e = 0; e < 8; ++e) atomicAdd(up + e, updacc[e]);
  if (c_u == 0) atomicAdd(asum + ((b * 8 + i_u) << 2) + h_u, asacc);
}

// ---------------- GRU cell ----------------
__global__ __launch_bounds__(256) void gru_kernel(const float* __restrict__ upd,
    const float* __restrict__ asum, const float* __restrict__ hsrc,
    const u16* __restrict__ wihb, const u16* __restrict__ whhb,
    const float* __restrict__ bih, const float* __restrict__ bhh,
    float* __restrict__ slots_ws, float* __restrict__ out_slots, int write_out){
  __shared__ float xs[256], hs[256];
  int row = blockIdx.x, t = threadIdx.x;
  float a = asum[(row << 2) + (t >> 6)];
  xs[t] = upd[(row << 8) + t] / (a + 1e-8f);   // fold attn j-normalization here
  hs[t] = hsrc[(row << 8) + t];
  __syncthreads();
  float gx[3], gh[3];
  #pragma unroll
  for (int g = 0; g < 3; ++g){
    const bf16x8* wr = (const bf16x8*)(wihb + (g * 256 + t) * 256);
    const bf16x8* wh = (const bf16x8*)(whhb + (g * 256 + t) * 256);
    float ax = 0.f, ah = 0.f;
    for (int c = 0; c < 32; ++c){
      bf16x8 w1 = wr[c], w2 = wh[c];
      #pragma unroll
      for (int e = 0; e < 8; ++e){
        ax += bf2f_s(w1[e]) * xs[c * 8 + e];
        ah += bf2f_s(w2[e]) * hs[c * 8 + e];
      }
    }
    gx[g] = ax + bih[g * 256 + t];
    gh[g] = ah + bhh[g * 256 + t];
  }
  float r = 1.f / (1.f + __expf(-(gx[0] + gh[0])));
  float z = 1.f / (1.f + __expf(-(gx[1] + gh[1])));
  float n = tanhf(gx[2] + r * gh[2]);
  float hnew = (1.f - z) * n + z * hs[t];
  slots_ws[(row << 8) + t] = hnew;
  if (write_out) out_slots[(row << 8) + t] = hnew;
}

extern "C" void kernel_launch(void* const* d_in, const int* in_sizes, int n_in,
                              void* d_out, int out_size, void* d_ws, size_t ws_size,
                              hipStream_t stream){
  const float* inputs = (const float*)d_in[0];
  const float* cond   = (const float*)d_in[1];
  const float* lniw   = (const float*)d_in[2];
  const float* lnib   = (const float*)d_in[3];
  const float* lnsw   = (const float*)d_in[4];
  const float* lnsb   = (const float*)d_in[5];
  const float* Wq     = (const float*)d_in[6];
  const float* Wk     = (const float*)d_in[7];
  const float* Wv     = (const float*)d_in[8];
  const float* wih    = (const float*)d_in[9];
  const float* whh    = (const float*)d_in[10];
  const float* bih    = (const float*)d_in[11];
  const float* bhh    = (const float*)d_in[12];

  char* ws = (char*)d_ws;
  u16*   xn       = (u16*)(ws);                       // 134,217,728 B
  u16*   kv       = (u16*)(ws + 134217728);           // 268,435,456 B
  float* q_ws     = (float*)(ws + 402653184);         // 524,288 B
  float* slots_ws = (float*)(ws + 403177472);         // 524,288 B
  float* upd_ws   = (float*)(ws + 403701760);         // 524,288 B
  float* asum_ws  = (float*)(ws + 404226048);         // 8,192 B (contiguous after upd)
  u16*   Bkv      = (u16*)(ws + 404234240);           // 262,144 B
  u16*   wihb     = (u16*)(ws + 404496384);           // 393,216 B
  u16*   whhb     = (u16*)(ws + 404889600);           // 393,216 B

  float* out       = (float*)d_out;
  float* out_slots = out;                       // [64][8][256]
  float* out_last  = out + 131072;              // [64][8][4096]
  float* out_stack = out + 131072 + 2097152;    // [3][64][8][4096]

  prep_kernel<<<dim3(256), dim3(256), 0, stream>>>(Wk, Wv, wih, whh, Bkv, wihb, whhb);
  ln_in_kernel<<<dim3(65536), dim3(256), 0, stream>>>(inputs, lniw, lnib, xn);
  gemm_kv<<<dim3(8192), dim3(256), 0, stream>>>(xn, Bkv, kv);
  for (int it = 0; it < 3; ++it){
    const float* ssrc = (it == 0) ? cond : slots_ws;
    q_kernel<<<dim3(512), dim3(256), 0, stream>>>(ssrc, lnsw, lnsb, Wq, q_ws);
    hipMemsetAsync(upd_ws, 0, 524288 + 8192, stream);
    iter_kernel<<<dim3(1024), dim3(256), 0, stream>>>(kv, q_ws, upd_ws, asum_ws,
        out_stack + (long)it * 2097152, out_last, (it == 2) ? 1 : 0);
    gru_kernel<<<dim3(512), dim3(256), 0, stream>>>(upd_ws, asum_ws, ssrc, wihb, whhb,
        bih, bhh, slots_ws, out_slots, (it == 2) ? 1 : 0);
  }
}

// Round 7
// 1157.536 us; speedup vs baseline: 1.0121x; 1.0121x over previous
//
#include <hip/hip_runtime.h>
#include <hip/hip_bf16.h>

// SlotAttention: B=64, N=4096, FEAT=DIM=KVQ=256, HEADS=4, SLOTS=8, ITERS=3, DPH=64
// r7 = r6 resubmit (round-6 was a broker acquisition timeout; kernel never ran).
// r6 = r1 base (known to run/pass on this infra; bf16 KV, NO fp8 builtins) +
//   (a) XCD-bijective gemm grid swizzle (A-tile L2 reuse),
//   (b) q+zeroing fused into gru/q kernels: 10 dispatches, no memsets.
// kv row j = 1024 B bf16 = 64 x 16B granules [k:0..31 | v:32..63],
// phys granule = logical ^ (j&7) (XOR within each 8-granule group).

typedef unsigned int u32;
typedef unsigned short u16;
typedef short bf16x8 __attribute__((ext_vector_type(8)));
typedef float f32x4 __attribute__((ext_vector_type(4)));

#define SCALE_ 0.125f

__device__ inline u16 f2bf(float f){
  u32 x = __float_as_uint(f);
  return (u16)((x + 0x7fffu + ((x >> 16) & 1u)) >> 16);
}
__device__ inline float bf2f_s(short h){ return __uint_as_float(((u32)(u16)h) << 16); }

__device__ inline void gload16(const void* g, void* l){
  __builtin_amdgcn_global_load_lds((const __attribute__((address_space(1))) u32*)g,
                                   (__attribute__((address_space(3))) u32*)l, 16, 0, 0);
}

// ---------------- prep: bf16 weight casts ----------------
__global__ void prep_kernel(const float* __restrict__ Wk, const float* __restrict__ Wv,
                            const float* __restrict__ wih, const float* __restrict__ whh,
                            u16* __restrict__ Bkv, u16* __restrict__ wihb, u16* __restrict__ whhb){
  int t = blockIdx.x * 256 + threadIdx.x;
  int stride = gridDim.x * 256;
  for (int idx = t; idx < 512 * 256; idx += stride){
    int n = idx >> 8, c = idx & 255;
    float v = (n < 256) ? Wk[(n << 8) + c] : Wv[((n - 256) << 8) + c];
    Bkv[idx] = f2bf(v);
  }
  for (int idx = t; idx < 768 * 256; idx += stride){
    wihb[idx] = f2bf(wih[idx]);
    whhb[idx] = f2bf(whh[idx]);
  }
}

// ---------------- LayerNorm(inputs) -> bf16 ----------------
__global__ __launch_bounds__(256) void ln_in_kernel(const float* __restrict__ x,
    const float* __restrict__ w, const float* __restrict__ bb, u16* __restrict__ xn){
  int wid = threadIdx.x >> 6, lane = threadIdx.x & 63;
  long row = (long)blockIdx.x * 4 + wid;   // 262144 rows, one per wave
  const float4* xr = (const float4*)(x + row * 256);
  float4 v = xr[lane];
  float s  = v.x + v.y + v.z + v.w;
  float s2 = v.x*v.x + v.y*v.y + v.z*v.z + v.w*v.w;
  #pragma unroll
  for (int m = 1; m < 64; m <<= 1){ s += __shfl_xor(s, m); s2 += __shfl_xor(s2, m); }
  float mu = s * (1.f/256.f);
  float rstd = rsqrtf(s2 * (1.f/256.f) - mu*mu + 1e-5f);
  float4 wv = ((const float4*)w)[lane];
  float4 bv = ((const float4*)bb)[lane];
  ushort4 o;
  o.x = f2bf((v.x - mu) * rstd * wv.x + bv.x);
  o.y = f2bf((v.y - mu) * rstd * wv.y + bv.y);
  o.z = f2bf((v.z - mu) * rstd * wv.z + bv.z);
  o.w = f2bf((v.w - mu) * rstd * wv.w + bv.w);
  *(ushort4*)(xn + row * 256 + lane * 4) = o;
}

// ---------------- GEMM: KV = xn @ Bkv^T, swizzled bf16 out ----------------
// Grid 8192 = 2048 mt x 4 nt. XCD-bijective swizzle: id&7 = XCD, the 4 nt-blocks
// of one mt get consecutive ids on the SAME XCD (A-tile L2 reuse; B L2-resident).
__global__ __launch_bounds__(256) void gemm_kv(const u16* __restrict__ A,
                                               const u16* __restrict__ Bm,
                                               u16* __restrict__ kv){
  __shared__ u16 smem[16384];             // 32 KB: A[128][64] + B[128][64], reused as C[128][128]
  u16* Al = smem;
  u16* Bl = smem + 8192;
  int tid = threadIdx.x, wid = tid >> 6, lane = tid & 63;
  int id = blockIdx.x;
  int xcd = id & 7;
  int lid = id >> 3;                      // 0..1023 per XCD
  long mt = (long)xcd * 256 + (lid >> 2);
  int nt = lid & 3;
  long m0 = mt * 128;
  int n0 = nt * 128;
  f32x4 acc[4][4] = {};
  int msub = (wid & 1) * 64, nsub = (wid >> 1) * 64;
  for (int kt = 0; kt < 4; ++kt){
    const char* Ag = (const char*)(A + m0 * 256 + kt * 64);
    const char* Bg = (const char*)(Bm + (long)n0 * 256 + kt * 64);
    #pragma unroll
    for (int p = 0; p < 4; ++p){
      int r0 = wid * 32 + p * 8;
      gload16(Ag + (long)(r0 + (lane >> 3)) * 512 + (lane & 7) * 16, (char*)Al + r0 * 128);
      gload16(Bg + (long)(r0 + (lane >> 3)) * 512 + (lane & 7) * 16, (char*)Bl + r0 * 128);
    }
    __syncthreads();
    #pragma unroll
    for (int kk = 0; kk < 2; ++kk){
      bf16x8 af[4], bfr[4];
      #pragma unroll
      for (int mi = 0; mi < 4; ++mi)
        af[mi] = *(const bf16x8*)(Al + (msub + mi*16 + (lane & 15)) * 64 + kk * 32 + (lane >> 4) * 8);
      #pragma unroll
      for (int ni = 0; ni < 4; ++ni)
        bfr[ni] = *(const bf16x8*)(Bl + (nsub + ni*16 + (lane & 15)) * 64 + kk * 32 + (lane >> 4) * 8);
      #pragma unroll
      for (int mi = 0; mi < 4; ++mi)
        #pragma unroll
        for (int ni = 0; ni < 4; ++ni)
          acc[mi][ni] = __builtin_amdgcn_mfma_f32_16x16x32_bf16(af[mi], bfr[ni], acc[mi][ni], 0, 0, 0);
    }
    __syncthreads();
  }
  // Epilogue: stage to LDS bf16 tile, then coalesced swizzled global writes.
  u16* Ct = smem;                          // [128][128]
  #pragma unroll
  for (int mi = 0; mi < 4; ++mi){
    #pragma unroll
    for (int ni = 0; ni < 4; ++ni){
      int col = nsub + ni*16 + (lane & 15);
      #pragma unroll
      for (int r = 0; r < 4; ++r){
        int rowm = msub + mi*16 + (lane >> 4) * 4 + r;
        Ct[rowm * 128 + col] = f2bf(acc[mi][ni][r]);
      }
    }
  }
  __syncthreads();
  // KV row = 1024B = 64 x 16B granules. phys granule = logical ^ (j&7).
  #pragma unroll
  for (int p = 0; p < 8; ++p){
    int g = p * 256 + tid;
    int row = g >> 4, pw = g & 15;
    long m = m0 + row;
    int j = (int)(m & 4095);
    int lloc = pw ^ (j & 7);
    uint4 val = *(const uint4*)(Ct + row * 128 + lloc * 8);
    *(uint4*)((char*)kv + m * 1024 + n0 * 2 + pw * 16) = val;
  }
}

// ---------------- q0 = LN(cond) @ Wq^T * SCALE  (+ zero upd/asum for iter 0) ----
__global__ __launch_bounds__(256) void q_kernel(const float* __restrict__ ssrc,
    const float* __restrict__ lnw, const float* __restrict__ lnb,
    const float* __restrict__ Wq, float* __restrict__ qout,
    float* __restrict__ upd_z, float* __restrict__ asum_z){
  __shared__ float sn[256];
  __shared__ float red[8];
  int row = blockIdx.x, t = threadIdx.x;
  int wid = t >> 6, lane = t & 63;
  float x = ssrc[row * 256 + t];
  float s = x, s2 = x * x;
  #pragma unroll
  for (int m = 1; m < 64; m <<= 1){ s += __shfl_xor(s, m); s2 += __shfl_xor(s2, m); }
  if (lane == 0){ red[wid] = s; red[4 + wid] = s2; }
  __syncthreads();
  s  = red[0] + red[1] + red[2] + red[3];
  s2 = red[4] + red[5] + red[6] + red[7];
  float mu = s * (1.f/256.f);
  float rstd = rsqrtf(s2 * (1.f/256.f) - mu*mu + 1e-5f);
  sn[t] = (x - mu) * rstd * lnw[t] + lnb[t];
  __syncthreads();
  const float4* wr = (const float4*)(Wq + t * 256);
  float acc = 0.f;
  #pragma unroll 8
  for (int c = 0; c < 64; ++c){
    float4 wv = wr[c];
    acc += wv.x * sn[c*4] + wv.y * sn[c*4+1] + wv.z * sn[c*4+2] + wv.w * sn[c*4+3];
  }
  qout[row * 256 + t] = acc * SCALE_;
  upd_z[(row << 8) + t] = 0.f;
  if (t < 4) asum_z[(row << 2) + t] = 0.f;
}

// ---------------- fused dots + softmax + attn-out + updates (bf16 KV) --------
// grid = 64 b * 16 blocks; each block: 8 tiles of 32 j. 256 thr = 4 waves.
__global__ __launch_bounds__(256) void iter_kernel(
    const u16* __restrict__ kv, const float* __restrict__ qg,
    float* __restrict__ upd, float* __restrict__ asum,
    float* __restrict__ out_stack, float* __restrict__ out_last, int write_last){
  __shared__ u16 kvl[32 * 512];     // 32 KB, pre-swizzled rows
  __shared__ float ql[2048];        // q[b]: [i][h][d]
  __shared__ float expl[1024];      // [j][(h*8+i)^j]
  __shared__ float rtot[32];
  int tid = threadIdx.x, wid = tid >> 6, lane = tid & 63;
  int b = blockIdx.x >> 4;
  int blk = blockIdx.x & 15;

  {
    const char* qsrc = (const char*)(qg + b * 2048);
    #pragma unroll
    for (int p = 0; p < 2; ++p){
      int seg = wid * 2 + p;
      gload16(qsrc + seg * 1024 + lane * 16, (char*)ql + seg * 1024);
    }
  }
  float updacc[8];
  #pragma unroll
  for (int e = 0; e < 8; ++e) updacc[e] = 0.f;
  float asacc = 0.f;
  int i_u = tid >> 5, h_u = (tid >> 3) & 3, c_u = tid & 7;
  int jj = lane & 31, half = lane >> 5, h = wid;

  for (int tile = 0; tile < 8; ++tile){
    int j0 = (blk * 8 + tile) * 32;
    const char* src = (const char*)(kv + ((long)b * 4096 + j0) * 512);
    #pragma unroll
    for (int p = 0; p < 8; ++p){
      int seg = wid * 8 + p;
      gload16(src + seg * 1024 + lane * 16, (char*)kvl + seg * 1024);
    }
    __syncthreads();
    // dots: wave h, lane = (jj, half); each half does 4 of 8 k-granules
    float dots[8];
    #pragma unroll
    for (int i = 0; i < 8; ++i) dots[i] = 0.f;
    #pragma unroll
    for (int cc = 0; cc < 4; ++cc){
      int c = half * 4 + cc;
      int gq = jj * 64 + ((h * 8 + c) ^ (jj & 7));
      bf16x8 kvv = *(const bf16x8*)(kvl + gq * 8);
      float kf[8];
      #pragma unroll
      for (int e = 0; e < 8; ++e) kf[e] = bf2f_s(kvv[e]);
      #pragma unroll
      for (int i = 0; i < 8; ++i){
        const float4* q4 = (const float4*)(ql + ((i * 4 + h) << 6) + c * 8);
        float4 qa = q4[0], qb = q4[1];
        dots[i] += qa.x*kf[0] + qa.y*kf[1] + qa.z*kf[2] + qa.w*kf[3]
                 + qb.x*kf[4] + qb.y*kf[5] + qb.z*kf[6] + qb.w*kf[7];
      }
    }
    #pragma unroll
    for (int i = 0; i < 8; ++i) dots[i] += __shfl_xor(dots[i], 32);
    float ev[8];
    #pragma unroll
    for (int i = 0; i < 8; ++i) ev[i] = __expf(dots[i]);   // |dots|<~1: no max-sub needed
    #pragma unroll
    for (int r = 0; r < 4; ++r){
      int i = half * 4 + r;
      expl[jj * 32 + ((h * 8 + i) ^ jj)] = ev[i];
    }
    __syncthreads();
    // total + attn-mean output (wave 0, 32 lanes)
    if (wid == 0 && lane < 32){
      int j = lane;
      float tot = 0.f; float si[8];
      #pragma unroll
      for (int i = 0; i < 8; ++i) si[i] = 0.f;
      #pragma unroll
      for (int h2 = 0; h2 < 4; ++h2){
        #pragma unroll
        for (int i = 0; i < 8; ++i){
          float v = expl[j * 32 + ((h2 * 8 + i) ^ j)];
          tot += v; si[i] += v;
        }
      }
      float rt = 1.f / tot;
      rtot[j] = rt;
      long obase = ((long)b * 8) * 4096 + j0 + j;
      #pragma unroll
      for (int i = 0; i < 8; ++i){
        float o = 0.25f * si[i] * rt;
        out_stack[obase + (long)i * 4096] = o;
        if (write_last) out_last[obase + (long)i * 4096] = o;
      }
    }
    __syncthreads();
    // updates: thread = (i_u, h_u, c_u); v-granule broadcast across i
    #pragma unroll 4
    for (int j = 0; j < 32; ++j){
      float at = expl[j * 32 + ((h_u * 8 + i_u) ^ j)] * rtot[j];
      int gv = j * 64 + ((32 + h_u * 8 + c_u) ^ (j & 7));
      bf16x8 vv = *(const bf16x8*)(kvl + gv * 8);
      #pragma unroll
      for (int e = 0; e < 8; ++e) updacc[e] += at * bf2f_s(vv[e]);
      if (c_u == 0) asacc += at;
    }
    __syncthreads();
  }
  float* up = upd + (((long)b * 8 + i_u) << 8) + h_u * 64 + c_u * 8;
  #pragma unroll
  for (int e = 0; e < 8; ++e) atomicAdd(up + e, updacc[e]);
  if (c_u == 0) atomicAdd(asum + ((b * 8 + i_u) << 2) + h_u, asacc);
}

// ---------------- GRU cell (+ fused q for next iter, + zero next upd/asum) ----
__global__ __launch_bounds__(256) void gru_kernel(const float* __restrict__ upd,
    const float* __restrict__ asum, const float* __restrict__ hsrc,
    const u16* __restrict__ wihb, const u16* __restrict__ whhb,
    const float* __restrict__ bih, const float* __restrict__ bhh,
    const float* __restrict__ lnsw, const float* __restrict__ lnsb,
    const float* __restrict__ Wq,
    float* __restrict__ slots_ws, float* __restrict__ q_ws,
    float* __restrict__ out_slots, float* __restrict__ upd_z,
    float* __restrict__ asum_z, int flags){   // 1=write slots out, 2=do q, 4=zero next
  __shared__ float xs[256], hs[256], sn[256], red[8];
  int row = blockIdx.x, t = threadIdx.x;
  float a = asum[(row << 2) + (t >> 6)];
  xs[t] = upd[(row << 8) + t] / (a + 1e-8f);   // fold attn j-normalization here
  hs[t] = hsrc[(row << 8) + t];
  __syncthreads();
  float gx[3], gh[3];
  #pragma unroll
  for (int g = 0; g < 3; ++g){
    const bf16x8* wr = (const bf16x8*)(wihb + (g * 256 + t) * 256);
    const bf16x8* wh = (const bf16x8*)(whhb + (g * 256 + t) * 256);
    float ax = 0.f, ah = 0.f;
    for (int c = 0; c < 32; ++c){
      bf16x8 w1 = wr[c], w2 = wh[c];
      #pragma unroll
      for (int e = 0; e < 8; ++e){
        ax += bf2f_s(w1[e]) * xs[c * 8 + e];
        ah += bf2f_s(w2[e]) * hs[c * 8 + e];
      }
    }
    gx[g] = ax + bih[g * 256 + t];
    gh[g] = ah + bhh[g * 256 + t];
  }
  float r = 1.f / (1.f + __expf(-(gx[0] + gh[0])));
  float z = 1.f / (1.f + __expf(-(gx[1] + gh[1])));
  float n = tanhf(gx[2] + r * gh[2]);
  float hnew = (1.f - z) * n + z * hs[t];
  slots_ws[(row << 8) + t] = hnew;
  if (flags & 1) out_slots[(row << 8) + t] = hnew;
  if (flags & 4){
    upd_z[(row << 8) + t] = 0.f;
    if (t < 4) asum_z[(row << 2) + t] = 0.f;
  }
  if (flags & 2){
    int wid = t >> 6, lane = t & 63;
    float s = hnew, s2 = hnew * hnew;
    #pragma unroll
    for (int m = 1; m < 64; m <<= 1){ s += __shfl_xor(s, m); s2 += __shfl_xor(s2, m); }
    if (lane == 0){ red[wid] = s; red[4 + wid] = s2; }
    __syncthreads();
    s  = red[0] + red[1] + red[2] + red[3];
    s2 = red[4] + red[5] + red[6] + red[7];
    float mu = s * (1.f/256.f);
    float rstd = rsqrtf(s2 * (1.f/256.f) - mu*mu + 1e-5f);
    sn[t] = (hnew - mu) * rstd * lnsw[t] + lnsb[t];
    __syncthreads();
    const float4* wr = (const float4*)(Wq + t * 256);
    float acc = 0.f;
    #pragma unroll 8
    for (int c = 0; c < 64; ++c){
      float4 wv = wr[c];
      acc += wv.x * sn[c*4] + wv.y * sn[c*4+1] + wv.z * sn[c*4+2] + wv.w * sn[c*4+3];
    }
    q_ws[(row << 8) + t] = acc * SCALE_;
  }
}

extern "C" void kernel_launch(void* const* d_in, const int* in_sizes, int n_in,
                              void* d_out, int out_size, void* d_ws, size_t ws_size,
                              hipStream_t stream){
  const float* inputs = (const float*)d_in[0];
  const float* cond   = (const float*)d_in[1];
  const float* lniw   = (const float*)d_in[2];
  const float* lnib   = (const float*)d_in[3];
  const float* lnsw   = (const float*)d_in[4];
  const float* lnsb   = (const float*)d_in[5];
  const float* Wq     = (const float*)d_in[6];
  const float* Wk     = (const float*)d_in[7];
  const float* Wv     = (const float*)d_in[8];
  const float* wih    = (const float*)d_in[9];
  const float* whh    = (const float*)d_in[10];
  const float* bih    = (const float*)d_in[11];
  const float* bhh    = (const float*)d_in[12];

  char* ws = (char*)d_ws;
  u16*   xn       = (u16*)(ws);                       // 134,217,728 B
  u16*   kv       = (u16*)(ws + 134217728);           // 268,435,456 B (bf16)
  float* q_ws     = (float*)(ws + 402653184);         // 524,288 B
  float* slots_ws = (float*)(ws + 403177472);         // 524,288 B
  float* upd_ws   = (float*)(ws + 403701760);         // 524,288 B
  float* asum_ws  = (float*)(ws + 404226048);         // 8,192 B
  u16*   Bkv      = (u16*)(ws + 404234240);           // 262,144 B
  u16*   wihb     = (u16*)(ws + 404496384);           // 393,216 B
  u16*   whhb     = (u16*)(ws + 404889600);           // 393,216 B

  float* out       = (float*)d_out;
  float* out_slots = out;                       // [64][8][256]
  float* out_last  = out + 131072;              // [64][8][4096]
  float* out_stack = out + 131072 + 2097152;    // [3][64][8][4096]

  prep_kernel<<<dim3(256), dim3(256), 0, stream>>>(Wk, Wv, wih, whh, Bkv, wihb, whhb);
  ln_in_kernel<<<dim3(65536), dim3(256), 0, stream>>>(inputs, lniw, lnib, xn);
  gemm_kv<<<dim3(8192), dim3(256), 0, stream>>>(xn, Bkv, kv);
  q_kernel<<<dim3(512), dim3(256), 0, stream>>>(cond, lnsw, lnsb, Wq, q_ws, upd_ws, asum_ws);
  for (int it = 0; it < 3; ++it){
    const float* ssrc = (it == 0) ? cond : slots_ws;
    iter_kernel<<<dim3(1024), dim3(256), 0, stream>>>(kv, q_ws, upd_ws, asum_ws,
        out_stack + (long)it * 2097152, out_last, (it == 2) ? 1 : 0);
    int flags = (it == 2) ? 1 : (2 | 4);
    gru_kernel<<<dim3(512), dim3(256), 0, stream>>>(upd_ws, asum_ws, ssrc, wihb, whhb,
        bih, bhh, lnsw, lnsb, Wq, slots_ws, q_ws, out_slots, upd_ws, asum_ws, flags);
  }
}